// Round 18
// baseline (115.715 us; speedup 1.0000x reference)
//
#include <hip/hip_runtime.h>
#include <hip/hip_bf16.h>
#include <hip/hip_fp16.h>

// Problem constants
#define S    2048
#define ND   128
#define NA   16
#define H    8
#define C    32
#define NH   24            // 3*H heads total
#define VD   128           // value dim per head
#define KQ_STRIDE (NH*C)   // 768 elems per row of K/Q
#define SCALE 0.3535533905932738f   // 1/sqrt(8)
// exp2-domain folding: scores arrive pre-multiplied by log2(e)
#define KSC 0.5101275365575154f     // SCALE * log2(e)  (folded into K)
#define GSC 0.7142321096986785f     // sqrt(KSC)        (folded into G; squares -> KSC)

typedef __attribute__((ext_vector_type(8))) short short8;
typedef __attribute__((ext_vector_type(4))) short s4v;
typedef __attribute__((ext_vector_type(4))) float f32x4;

typedef __hip_bfloat16 bf16;

__device__ __forceinline__ short bf16_bits(float x) {
  bf16 h = __float2bfloat16(x);
  union { bf16 h; short s; } u; u.h = h; return u.s;
}

// Raw hardware 2^x (v_exp_f32, trans pipe, 1 instruction) — R16 win.
__device__ __forceinline__ float fexp2(float x) {
  float r;
  asm("v_exp_f32 %0, %1" : "=v"(r) : "v"(x));
  return r;
}

// 3-input max in one instruction (T17, drop-in arithmetic).
__device__ __forceinline__ float fmax3(float a, float b, float c) {
  float r;
  asm("v_max3_f32 %0, %1, %2, %3" : "=v"(r) : "v"(a), "v"(b), "v"(c));
  return r;
}

// pack two fp32 -> one uint of 2 bf16 (RNE) — for in-reg operand conversion
__device__ __forceinline__ unsigned int cvtpk(float lo, float hi) {
  unsigned int r;
  asm("v_cvt_pk_bf16_f32 %0, %1, %2" : "=v"(r) : "v"(lo), "v"(hi));
  return r;
}

// load 8 consecutive fp32 and convert to a bf16 short8 fragment
__device__ __forceinline__ short8 load8_f32_bf16(const float* p) {
  const float4 a = *reinterpret_cast<const float4*>(p);
  const float4 b = *reinterpret_cast<const float4*>(p + 4);
  union { unsigned int u[4]; short8 s; } r;
  r.u[0] = cvtpk(a.x, a.y);
  r.u[1] = cvtpk(a.z, a.w);
  r.u[2] = cvtpk(b.x, b.y);
  r.u[3] = cvtpk(b.z, b.w);
  return r.s;
}

// global->LDS direct copy, 16 B per lane (lds dest = uniform base + lane*16)
__device__ __forceinline__ void gload_lds16(const bf16* g, bf16* l) {
  __builtin_amdgcn_global_load_lds(
      (const __attribute__((address_space(1))) void*)g,
      (__attribute__((address_space(3))) void*)l, 16, 0, 0);
}

// ---------------------------------------------------------------------------
// prep (rotg only): M_h = (W_rk_h^T W_rq_h)*GSC; G_i = rot_i^T M_h.
// bf16 hi/lo splits so rot scores run on the SAME MFMA path as nodes/aux.
// ---------------------------------------------------------------------------
__global__ __launch_bounds__(256) void rotg_kernel(
    const float* __restrict__ rot, const float* __restrict__ Wr,
    bf16* __restrict__ Ghat, bf16* __restrict__ Rhat) {
  __shared__ float M[8][4][4];
  const int t = threadIdx.x;
  if (t < 128) {
    const int hl = t >> 4, a = (t >> 2) & 3, b = t & 3;
    float s = 0.0f;
#pragma unroll
    for (int c = 0; c < 32; ++c)
      s += Wr[(size_t)(hl * 64 + c) * 4 + a] *
           Wr[(size_t)(hl * 64 + 32 + c) * 4 + b];
    M[hl][a][b] = s * GSC;
  }
  __syncthreads();
  const int i  = blockIdx.x * 32 + (t >> 3);
  const int hl = t & 7;
  const float4 rv = *reinterpret_cast<const float4*>(rot + (size_t)i * 4);
  float g[4];
#pragma unroll
  for (int b = 0; b < 4; ++b)
    g[b] = rv.x * M[hl][0][b] + rv.y * M[hl][1][b]
         + rv.z * M[hl][2][b] + rv.w * M[hl][3][b];

  short hi[4], lo[4];
#pragma unroll
  for (int b = 0; b < 4; ++b) {
    bf16 hb = __float2bfloat16(g[b]);
    hi[b] = bf16_bits(g[b]);
    lo[b] = bf16_bits(g[b] - __bfloat162float(hb));
  }
  const short8 zz = {0, 0, 0, 0, 0, 0, 0, 0};
  short8 w0 = {hi[0], hi[1], hi[2], hi[3], lo[0], lo[1], lo[2], lo[3]};
  short8 w1 = {hi[0], hi[1], hi[2], hi[3], 0, 0, 0, 0};
  bf16* gp = Ghat + ((size_t)hl * S + i) * 32;
  *reinterpret_cast<short8*>(gp)      = w0;
  *reinterpret_cast<short8*>(gp + 8)  = w1;
  *reinterpret_cast<short8*>(gp + 16) = zz;
  *reinterpret_cast<short8*>(gp + 24) = zz;

  if (hl == 0) {
    float rr[4] = {rv.x, rv.y, rv.z, rv.w};
    short rh[4], rl[4];
#pragma unroll
    for (int b = 0; b < 4; ++b) {
      bf16 hb = __float2bfloat16(rr[b]);
      rh[b] = bf16_bits(rr[b]);
      rl[b] = bf16_bits(rr[b] - __bfloat162float(hb));
    }
    short8 r0 = {rh[0], rh[1], rh[2], rh[3], rh[0], rh[1], rh[2], rh[3]};
    short8 r1 = {rl[0], rl[1], rl[2], rl[3], 0, 0, 0, 0};
    bf16* rp = Rhat + (size_t)i * 32;
    *reinterpret_cast<short8*>(rp)      = r0;
    *reinterpret_cast<short8*>(rp + 8)  = r1;
    *reinterpret_cast<short8*>(rp + 16) = zz;
    *reinterpret_cast<short8*>(rp + 24) = zz;
  }
}

// ---------------------------------------------------------------------------
// Fused projection GEMMs reading fp32 inputs DIRECTLY (in-reg bf16 convert —
// the standalone convert pass and its 3.2 MB round-trip are gone).
// y in [0,8):  nodes k/q (KE=128, K scaled by KSC)
// y in [8,16): aux   k/q (K=16 padded to 32 in-reg: g4>=2 lanes feed zeros)
// y in [16,64): val^T    (KE=128)
// ---------------------------------------------------------------------------
__global__ __launch_bounds__(256) void proj_all_kernel(
    const float* __restrict__ nodes, const float* __restrict__ aux,
    const float* __restrict__ Wn, const float* __restrict__ Wa,
    const float* __restrict__ Wv,
    const float* __restrict__ bn, const float* __restrict__ ba,
    const float* __restrict__ bv,
    bf16* __restrict__ Kb, bf16* __restrict__ Qb, bf16* __restrict__ Vt) {
  const int t = threadIdx.x;
  const int lane = t & 63;
  const int w = t >> 6;
  const int l15 = lane & 15, g4 = lane >> 4;
  const int i0 = blockIdx.x * 64 + w * 16;
  const int y  = blockIdx.y;

  f32x4 acc[4];
#pragma unroll
  for (int s = 0; s < 4; ++s) acc[s] = (f32x4){0.f, 0.f, 0.f, 0.f};

  if (y < 8 || y >= 16) {  // KE = 128 paths (nodes inputs)
    const float* B = (y < 8) ? Wn : Wv;
    const int o0 = (y < 8) ? y * 64 : (y - 16) * 64;
    const float* arow = nodes + (size_t)(i0 + l15) * ND + g4 * 8;
    const float* brow = B + (size_t)(o0 + l15) * ND + g4 * 8;
#pragma unroll
    for (int ks = 0; ks < 4; ++ks) {
      const short8 af = load8_f32_bf16(arow + ks * 32);
#pragma unroll
      for (int s = 0; s < 4; ++s) {
        const short8 bfr = load8_f32_bf16(brow + (size_t)s * 16 * ND + ks * 32);
        acc[s] = __builtin_amdgcn_mfma_f32_16x16x32_bf16(af, bfr, acc[s], 0, 0, 0);
      }
    }
    if (y < 8) {  // nodes k/q epilogue
#pragma unroll
      for (int s = 0; s < 4; ++s) {
        const int o = o0 + s * 16 + l15;
        const float bb = bn[o];
        const int head = (o >> 6);
        const int half = (o >> 5) & 1;
        const int c = o & 31;
        bf16* dst = half ? Qb : Kb;
        const float sc = half ? 1.0f : KSC;
#pragma unroll
        for (int r = 0; r < 4; ++r)
          dst[(size_t)(i0 + g4 * 4 + r) * KQ_STRIDE + head * C + c] =
              __float2bfloat16((acc[s][r] + bb) * sc);
      }
    } else {  // val^T epilogue
#pragma unroll
      for (int s = 0; s < 4; ++s) {
        const int o = o0 + s * 16 + l15;
        const float bb = bv[o];
        s4v pk;
#pragma unroll
        for (int r = 0; r < 4; ++r) pk[r] = bf16_bits(acc[s][r] + bb);
        *reinterpret_cast<s4v*>(Vt + (size_t)o * S + i0 + g4 * 4) = pk;
      }
    }
  } else {  // aux path: K=16 real cols, padded to 32 in-reg (exact)
    const int o0 = (y - 8) * 64;
    const short8 zz = {0, 0, 0, 0, 0, 0, 0, 0};
    short8 af = zz;
    if (g4 < 2)
      af = load8_f32_bf16(aux + (size_t)(i0 + l15) * NA + g4 * 8);
#pragma unroll
    for (int s = 0; s < 4; ++s) {
      short8 bfr = zz;
      if (g4 < 2)
        bfr = load8_f32_bf16(Wa + (size_t)(o0 + s * 16 + l15) * NA + g4 * 8);
      acc[s] = __builtin_amdgcn_mfma_f32_16x16x32_bf16(af, bfr, acc[s], 0, 0, 0);
    }
#pragma unroll
    for (int s = 0; s < 4; ++s) {
      const int o = o0 + s * 16 + l15;
      const float bb = ba[o];
      const int head = 8 + (o >> 6);
      const int half = (o >> 5) & 1;
      const int c = o & 31;
      bf16* dst = half ? Qb : Kb;
      const float sc = half ? 1.0f : KSC;
#pragma unroll
      for (int r = 0; r < 4; ++r)
        dst[(size_t)(i0 + g4 * 4 + r) * KQ_STRIDE + head * C + c] =
            __float2bfloat16((acc[s][r] + bb) * sc);
    }
  }
}

// ---------------------------------------------------------------------------
// Swapped-layout MFMA flash attention (R16-proven structure, verbatim except
// fmax3 in the lane-local max tree): XCD head-grouped, 128-j macro-tiles,
// lazy softmax (hardware v_exp_f32, exp2 domain), defer-max, V via
// global_load_lds (pre-swizzled source), fp16 per-head partials.
// MODE 1: per-head fp16 O to Oph. MODE 2: atomicAdd float into out.
// ---------------------------------------------------------------------------
#define SF(q) sf[(q) >> 2][(q) & 3]
#define PSTR 76   // uint words per i-row

template <int MODE>
__global__ __launch_bounds__(256, 3) void attn_mfma_kernel(
    const bf16* __restrict__ Kb, const bf16* __restrict__ Qb,
    const bf16* __restrict__ Vt, const bf16* __restrict__ Ghat,
    const bf16* __restrict__ Rhat, __half* __restrict__ Oph,
    float* __restrict__ Opf) {
  // ---- XCD swizzle decode: id = within*8 + g; g -> heads [3g, 3g+3) ----
  const int id     = blockIdx.x;      // 0..767
  const int g      = id & 7;          // XCD under %8 round-robin
  const int within = id >> 3;         // 0..95
  const int h      = g * 3 + (within >> 5);
  const int i0     = (within & 31) * 64;

  const int t    = threadIdx.x;
  const int lane = t & 63;
  const int w    = t >> 6;
  const int l15  = lane & 15;
  const int g4   = lane >> 4;
  const bool isrot = (h >= 16);

  __shared__ __align__(16) bf16 Vs0[128 * 64];            // 16 KB each
  __shared__ __align__(16) bf16 Vs1[128 * 64];
  __shared__ __align__(16) unsigned int Ps[4][16][PSTR];  // 19 KB

  const bf16* kp; const bf16* qp; int qst;
  if (!isrot) {
    kp = Kb + h * C; qp = Qb + h * C; qst = KQ_STRIDE;
  } else {
    kp = Ghat + (size_t)(h - 16) * S * 32; qp = Rhat; qst = 32;
  }
  const int kst = isrot ? 32 : KQ_STRIDE;

  // B-frag: K row for this wave's i = i0 + w*16 + l15 (loop-invariant)
  const short8 kfrag = *reinterpret_cast<const short8*>(
      kp + (size_t)(i0 + w * 16 + l15) * kst + g4 * 8);

  float m = -1e30f, l = 0.0f;   // l is a PER-LANE partial (reduced at end)
  f32x4 oacc[8];
#pragma unroll
  for (int d = 0; d < 8; ++d) oacc[d] = (f32x4){0.f, 0.f, 0.f, 0.f};

  // ---- V staging source (pre-swizzled per-lane) ----
  const bf16* vglane = Vt + ((size_t)h * VD + w * 32 + (lane >> 3)) * S +
                       (((lane & 7) ^ ((lane >> 3) & 7)) << 3);
  const int vbase0 = l15 * 64 + (((g4 + 0) ^ (l15 & 7)) << 3);
  const int vbase1 = l15 * 64 + (((g4 + 4) ^ (l15 & 7)) << 3);

  const bf16* qlanebase = qp + (size_t)l15 * qst + g4 * 8;
  short8 qf[8];

  // ---- prologue: issue V gloads for macro 0 (both tiles); load Q macro 0 ----
  {
    bf16* d0 = Vs0 + (w << 11);
    bf16* d1 = Vs1 + (w << 11);
    gload_lds16(vglane,           d0);
    gload_lds16(vglane + 8 * S,   d0 + 512);
    gload_lds16(vglane + 16 * S,  d0 + 1024);
    gload_lds16(vglane + 24 * S,  d0 + 1536);
    gload_lds16(vglane + 64,          d1);
    gload_lds16(vglane + 64 + 8 * S,  d1 + 512);
    gload_lds16(vglane + 64 + 16 * S, d1 + 1024);
    gload_lds16(vglane + 64 + 24 * S, d1 + 1536);
  }
#pragma unroll
  for (int u = 0; u < 8; ++u)
    qf[u] = *reinterpret_cast<const short8*>(qlanebase + (size_t)(u * 16) * qst);

  for (int mt = 0; mt < S / 128; ++mt) {
    // ---- A: QK for both tiles (8 MFMA), scores S^T[j][i] ----
    f32x4 sf[8];
    {
      const f32x4 z = {0.f, 0.f, 0.f, 0.f};
      __builtin_amdgcn_s_setprio(1);
#pragma unroll
      for (int u = 0; u < 8; ++u)
        sf[u] = __builtin_amdgcn_mfma_f32_16x16x32_bf16(qf[u], kfrag, z, 0, 0, 0);
      __builtin_amdgcn_s_setprio(0);
    }
    // ---- B: reload Q for next macro ----
    if (mt + 1 < S / 128) {
      const bf16* qn = qlanebase + (size_t)((mt + 1) * 128) * qst;
#pragma unroll
      for (int u = 0; u < 8; ++u)
        qf[u] = *reinterpret_cast<const short8*>(qn + (size_t)(u * 16) * qst);
    }

    // ---- C: lazy softmax over 32 scores ----
    if (isrot) {
#pragma unroll
      for (int u = 0; u < 8; ++u)
#pragma unroll
        for (int r = 0; r < 4; ++r) sf[u][r] *= sf[u][r];
    }
    // lane-local max: per-group max3+max, then 8->1 max3 tree
    float gm[8];
#pragma unroll
    for (int u = 0; u < 8; ++u)
      gm[u] = fmaxf(fmax3(sf[u][0], sf[u][1], sf[u][2]), sf[u][3]);
    const float h0 = fmax3(gm[0], gm[1], gm[2]);
    const float h1 = fmax3(gm[3], gm[4], gm[5]);
    const float h2 = fmaxf(gm[6], gm[7]);
    const float tm = fmax3(h0, h1, h2);
    // rescale check WITHOUT cross-lane reduce; row-max shfls only if firing
    if (__any(tm > m + 8.0f)) {
      float tmr = tm;
      tmr = fmaxf(tmr, __shfl_xor(tmr, 16));
      tmr = fmaxf(tmr, __shfl_xor(tmr, 32));
      const float mnew = fmaxf(m, tmr);
      const float corr = fexp2(m - mnew);
      m = mnew;
      l *= corr;
#pragma unroll
      for (int d = 0; d < 8; ++d)
#pragma unroll
        for (int r = 0; r < 4; ++r) oacc[d][r] *= corr;
    }
    // exp (independent) + lane-local sum tree into l partial
#pragma unroll
    for (int u = 0; u < 8; ++u)
#pragma unroll
      for (int r = 0; r < 4; ++r) sf[u][r] = fexp2(sf[u][r] - m);
    float sr[16];
#pragma unroll
    for (int q = 0; q < 16; ++q) sr[q] = SF(2 * q) + SF(2 * q + 1);
#pragma unroll
    for (int st = 8; st >= 1; st >>= 1)
#pragma unroll
      for (int q = 0; q < 8; ++q)
        if (q < st) sr[q] = sr[q] + sr[q + st];
    l += sr[0];

    // ---- pack P (both tiles) into Ps; per-wave region ----
#pragma unroll
    for (int sub = 0; sub < 8; ++sub) {
      unsigned int u0 = cvtpk(SF(4 * sub), SF(4 * sub + 1));
      unsigned int u1 = cvtpk(SF(4 * sub + 2), SF(4 * sub + 3));
      uint2 pk; pk.x = u0; pk.y = u1;
      const int col = (sub < 4 ? sub * 8 : 40 + (sub - 4) * 8) + g4 * 2;
      *reinterpret_cast<uint2*>(&Ps[w][l15][col]) = pk;
    }

    // ---- D: barrier (drains V gloads; P visible) ----
    __syncthreads();

    // ---- E: PV both tiles (32 MFMA) ----
    {
      union { uint4 u; short8 s; } pb0, pb1, pb2, pb3;
      pb0.u = *reinterpret_cast<const uint4*>(&Ps[w][l15][g4 * 4]);
      pb1.u = *reinterpret_cast<const uint4*>(&Ps[w][l15][16 + g4 * 4]);
      pb2.u = *reinterpret_cast<const uint4*>(&Ps[w][l15][40 + g4 * 4]);
      pb3.u = *reinterpret_cast<const uint4*>(&Ps[w][l15][56 + g4 * 4]);
      __builtin_amdgcn_s_setprio(1);
#pragma unroll
      for (int dsub = 0; dsub < 8; ++dsub) {
        const short8 va = *reinterpret_cast<const short8*>(
            &Vs0[vbase0 + dsub * 1024]);
        oacc[dsub] =
            __builtin_amdgcn_mfma_f32_16x16x32_bf16(va, pb0.s, oacc[dsub], 0, 0, 0);
      }
#pragma unroll
      for (int dsub = 0; dsub < 8; ++dsub) {
        const short8 va = *reinterpret_cast<const short8*>(
            &Vs0[vbase1 + dsub * 1024]);
        oacc[dsub] =
            __builtin_amdgcn_mfma_f32_16x16x32_bf16(va, pb1.s, oacc[dsub], 0, 0, 0);
      }
#pragma unroll
      for (int dsub = 0; dsub < 8; ++dsub) {
        const short8 va = *reinterpret_cast<const short8*>(
            &Vs1[vbase0 + dsub * 1024]);
        oacc[dsub] =
            __builtin_amdgcn_mfma_f32_16x16x32_bf16(va, pb2.s, oacc[dsub], 0, 0, 0);
      }
#pragma unroll
      for (int dsub = 0; dsub < 8; ++dsub) {
        const short8 va = *reinterpret_cast<const short8*>(
            &Vs1[vbase1 + dsub * 1024]);
        oacc[dsub] =
            __builtin_amdgcn_mfma_f32_16x16x32_bf16(va, pb3.s, oacc[dsub], 0, 0, 0);
      }
      __builtin_amdgcn_s_setprio(0);
    }

    // ---- F: barrier (all waves' PV reads done) ----
    __syncthreads();

    // ---- G: issue async V gloads for next macro ----
    if (mt + 1 < S / 128) {
      const bf16* gsrc = vglane + (size_t)(mt + 1) * 128;
      bf16* d0 = Vs0 + (w << 11);
      bf16* d1 = Vs1 + (w << 11);
      gload_lds16(gsrc,           d0);
      gload_lds16(gsrc + 8 * S,   d0 + 512);
      gload_lds16(gsrc + 16 * S,  d0 + 1024);
      gload_lds16(gsrc + 24 * S,  d0 + 1536);
      gload_lds16(gsrc + 64,          d1);
      gload_lds16(gsrc + 64 + 8 * S,  d1 + 512);
      gload_lds16(gsrc + 64 + 16 * S, d1 + 1024);
      gload_lds16(gsrc + 64 + 24 * S, d1 + 1536);
    }
  }

  // ---- epilogue: reduce per-lane l partials across the row's 4 lanes ----
  l += __shfl_xor(l, 16);
  l += __shfl_xor(l, 32);
  const float inv = 1.0f / l;
  const int irow = i0 + w * 16 + l15;
  if (MODE == 2) {
#pragma unroll
    for (int dsub = 0; dsub < 8; ++dsub)
#pragma unroll
      for (int r = 0; r < 4; ++r)
        atomicAdd(Opf + (size_t)irow * VD + dsub * 16 + g4 * 4 + r,
                  oacc[dsub][r] * inv);
  } else {
    __half* op = Oph + (size_t)h * (S * VD) + (size_t)irow * VD;
#pragma unroll
    for (int dsub = 0; dsub < 8; ++dsub) {
      __half h0 = __float2half(oacc[dsub][0] * inv);
      __half h1 = __float2half(oacc[dsub][1] * inv);
      __half h2 = __float2half(oacc[dsub][2] * inv);
      __half h3 = __float2half(oacc[dsub][3] * inv);
      __half2 p0 = __halves2half2(h0, h1);
      __half2 p1 = __halves2half2(h2, h3);
      uint2 u;
      u.x = *reinterpret_cast<unsigned int*>(&p0);
      u.y = *reinterpret_cast<unsigned int*>(&p1);
      *reinterpret_cast<uint2*>(op + dsub * 16 + g4 * 4) = u;
    }
  }
}

// Sum the 24 per-head fp16 partials into the final (S, 128) fp32 output.
__global__ __launch_bounds__(256) void reduce_out_kernel(
    const __half* __restrict__ Op, float* __restrict__ out) {
  const int idx2 = (blockIdx.x * 256 + threadIdx.x) * 2;
  float s0 = 0.0f, s1 = 0.0f;
#pragma unroll
  for (int hh = 0; hh < NH; ++hh) {
    const __half2 hv = *reinterpret_cast<const __half2*>(
        Op + (size_t)hh * (S * VD) + idx2);
    const float2 f = __half22float2(hv);
    s0 += f.x;
    s1 += f.y;
  }
  float2 o; o.x = s0; o.y = s1;
  *reinterpret_cast<float2*>(out + idx2) = o;
}

extern "C" void kernel_launch(void* const* d_in, const int* in_sizes, int n_in,
                              void* d_out, int out_size, void* d_ws, size_t ws_size,
                              hipStream_t stream) {
  const float* nodes = (const float*)d_in[0];
  const float* aux   = (const float*)d_in[1];
  const float* rot   = (const float*)d_in[2];
  const float* Wn    = (const float*)d_in[3];
  const float* bn    = (const float*)d_in[4];
  const float* Wa    = (const float*)d_in[5];
  const float* ba    = (const float*)d_in[6];
  const float* Wr    = (const float*)d_in[7];
  const float* Wv    = (const float*)d_in[8];
  const float* bv    = (const float*)d_in[9];
  float* out = (float*)d_out;

  char* ws = (char*)d_ws;
  const size_t off_Kb   = 0;
  const size_t off_Qb   = off_Kb + (size_t)S * KQ_STRIDE * 2;
  const size_t off_Vt   = off_Qb + (size_t)S * KQ_STRIDE * 2;
  const size_t off_Gh   = off_Vt + (size_t)NH * VD * S * 2;
  const size_t off_Rh   = off_Gh + (size_t)8 * S * 32 * 2;
  const size_t off_Op   = off_Rh + (size_t)S * 32 * 2;
  const size_t need1    = off_Op + (size_t)NH * S * VD * 2;   // fp16 partials

  bf16*  Kb = (bf16*)(ws + off_Kb);
  bf16*  Qb = (bf16*)(ws + off_Qb);
  bf16*  Vt = (bf16*)(ws + off_Vt);
  bf16*  Gh = (bf16*)(ws + off_Gh);
  bf16*  Rh = (bf16*)(ws + off_Rh);
  __half* Oph = (__half*)(ws + off_Op);

  rotg_kernel<<<S / 32, 256, 0, stream>>>(rot, Wr, Gh, Rh);

  proj_all_kernel<<<dim3(S / 64, 64), 256, 0, stream>>>(
      nodes, aux, Wn, Wa, Wv, bn, ba, bv, Kb, Qb, Vt);

  if (ws_size >= need1) {
    attn_mfma_kernel<1><<<dim3(768), 256, 0, stream>>>(
        Kb, Qb, Vt, Gh, Rh, Oph, nullptr);
    reduce_out_kernel<<<(S * VD) / 512, 256, 0, stream>>>(Oph, out);
  } else {
    hipMemsetAsync(d_out, 0, (size_t)out_size * sizeof(float), stream);
    attn_mfma_kernel<2><<<dim3(768), 256, 0, stream>>>(
        Kb, Qb, Vt, Gh, Rh, nullptr, out);
  }
}

// Round 19
// 100.951 us; speedup vs baseline: 1.1462x; 1.1462x over previous
//
#include <hip/hip_runtime.h>
#include <hip/hip_bf16.h>
#include <hip/hip_fp16.h>

// Problem constants
#define S    2048
#define ND   128
#define NA   16
#define H    8
#define C    32
#define NH   24            // 3*H heads total
#define VD   128           // value dim per head
#define KQ_STRIDE (NH*C)   // 768 elems per row of K/Q
#define SCALE 0.3535533905932738f   // 1/sqrt(8)
// exp2-domain folding: scores arrive pre-multiplied by log2(e)
#define KSC 0.5101275365575154f     // SCALE * log2(e)  (folded into K)
#define GSC 0.7142321096986785f     // sqrt(KSC)        (folded into G; squares -> KSC)

// bf16 conversion-buffer element counts (flat regions in ws)
#define AN_SZ (S*ND)
#define AA_SZ (S*32)
#define BN_SZ (512*ND)
#define BA_SZ (512*32)
#define BV_SZ (3072*ND)
#define CONV_TOTAL (AN_SZ + AA_SZ + BN_SZ + BA_SZ + BV_SZ)  // 802816
#define CONV_BLOCKS (CONV_TOTAL / 1024)                      // 784

typedef __attribute__((ext_vector_type(8))) short short8;
typedef __attribute__((ext_vector_type(4))) short s4v;
typedef __attribute__((ext_vector_type(4))) float f32x4;

typedef __hip_bfloat16 bf16;

__device__ __forceinline__ short bf16_bits(float x) {
  bf16 h = __float2bfloat16(x);
  union { bf16 h; short s; } u; u.h = h; return u.s;
}

// Raw hardware 2^x (v_exp_f32, trans pipe, 1 instruction) — R16 win.
// __builtin_exp2f without fast-math lowers to the ~20-instruction
// __ocml_exp2_f32 call (~600 VALU ops per macro-tile).
__device__ __forceinline__ float fexp2(float x) {
  float r;
  asm("v_exp_f32 %0, %1" : "=v"(r) : "v"(x));
  return r;
}

// global->LDS direct copy, 16 B per lane (lds dest = uniform base + lane*16)
__device__ __forceinline__ void gload_lds16(const bf16* g, bf16* l) {
  __builtin_amdgcn_global_load_lds(
      (const __attribute__((address_space(1))) void*)g,
      (__attribute__((address_space(3))) void*)l, 16, 0, 0);
}

// ---------------------------------------------------------------------------
// prep: blocks [0,784) cast nodes/Wn/Wv to bf16, zero-pad aux/Wa to K=32
// (amortize-once: each operand converted ONCE, then reused 32-64x as bf16 —
// R18 showed inline conversion re-reads cost ~14 us);
// blocks [784,848) rot-head precompute (M_h = W_rk^T W_rq * GSC,
// G_i = rot_i^T M_h, bf16 hi/lo splits for the unified MFMA path).
// ---------------------------------------------------------------------------
__global__ __launch_bounds__(256) void prep_kernel(
    const float* __restrict__ nodes, const float* __restrict__ aux,
    const float* __restrict__ Wn, const float* __restrict__ Wa,
    const float* __restrict__ Wv, const float* __restrict__ rot,
    const float* __restrict__ Wr, bf16* __restrict__ out,
    bf16* __restrict__ Ghat, bf16* __restrict__ Rhat) {
  const int t = threadIdx.x;
  if (blockIdx.x < CONV_BLOCKS) {
    const int base = (blockIdx.x * 256 + t) * 4;
#pragma unroll
    for (int u = 0; u < 4; ++u) {
      const int idx = base + u;
      int k = idx;
      float v;
      if (k < AN_SZ) {
        v = nodes[k];
      } else if ((k -= AN_SZ) < AA_SZ) {
        const int ccol = k & 31;
        v = (ccol < 16) ? aux[(size_t)(k >> 5) * NA + ccol] : 0.0f;
      } else if ((k -= AA_SZ) < BN_SZ) {
        v = Wn[k];
      } else if ((k -= BN_SZ) < BA_SZ) {
        const int ccol = k & 31;
        v = (ccol < 16) ? Wa[(size_t)(k >> 5) * NA + ccol] : 0.0f;
      } else {
        v = Wv[k - BA_SZ];
      }
      out[idx] = __float2bfloat16(v);
    }
  } else {
    __shared__ float M[8][4][4];
    if (t < 128) {
      const int hl = t >> 4, a = (t >> 2) & 3, b = t & 3;
      float s = 0.0f;
#pragma unroll
      for (int c = 0; c < 32; ++c)
        s += Wr[(size_t)(hl * 64 + c) * 4 + a] *
             Wr[(size_t)(hl * 64 + 32 + c) * 4 + b];
      M[hl][a][b] = s * GSC;
    }
    __syncthreads();
    const int i  = (blockIdx.x - CONV_BLOCKS) * 32 + (t >> 3);
    const int hl = t & 7;
    const float4 rv = *reinterpret_cast<const float4*>(rot + (size_t)i * 4);
    float g[4];
#pragma unroll
    for (int b = 0; b < 4; ++b)
      g[b] = rv.x * M[hl][0][b] + rv.y * M[hl][1][b]
           + rv.z * M[hl][2][b] + rv.w * M[hl][3][b];

    short hi[4], lo[4];
#pragma unroll
    for (int b = 0; b < 4; ++b) {
      bf16 hb = __float2bfloat16(g[b]);
      hi[b] = bf16_bits(g[b]);
      lo[b] = bf16_bits(g[b] - __bfloat162float(hb));
    }
    const short8 zz = {0, 0, 0, 0, 0, 0, 0, 0};
    short8 w0 = {hi[0], hi[1], hi[2], hi[3], lo[0], lo[1], lo[2], lo[3]};
    short8 w1 = {hi[0], hi[1], hi[2], hi[3], 0, 0, 0, 0};
    bf16* gp = Ghat + ((size_t)hl * S + i) * 32;
    *reinterpret_cast<short8*>(gp)      = w0;
    *reinterpret_cast<short8*>(gp + 8)  = w1;
    *reinterpret_cast<short8*>(gp + 16) = zz;
    *reinterpret_cast<short8*>(gp + 24) = zz;

    if (hl == 0) {
      float rr[4] = {rv.x, rv.y, rv.z, rv.w};
      short rh[4], rl[4];
#pragma unroll
      for (int b = 0; b < 4; ++b) {
        bf16 hb = __float2bfloat16(rr[b]);
        rh[b] = bf16_bits(rr[b]);
        rl[b] = bf16_bits(rr[b] - __bfloat162float(hb));
      }
      short8 r0 = {rh[0], rh[1], rh[2], rh[3], rh[0], rh[1], rh[2], rh[3]};
      short8 r1 = {rl[0], rl[1], rl[2], rl[3], 0, 0, 0, 0};
      bf16* rp = Rhat + (size_t)i * 32;
      *reinterpret_cast<short8*>(rp)      = r0;
      *reinterpret_cast<short8*>(rp + 8)  = r1;
      *reinterpret_cast<short8*>(rp + 16) = zz;
      *reinterpret_cast<short8*>(rp + 24) = zz;
    }
  }
}

// ---------------------------------------------------------------------------
// Fused projection GEMMs (bf16 operands): grid y decodes path.
// y in [0,8):  nodes k/q (KE=128, K scaled by KSC)
// y in [8,16): aux   k/q (KE=32,  K scaled)
// y in [16,64): val^T    (KE=128)
// ---------------------------------------------------------------------------
__global__ __launch_bounds__(256) void proj_all_kernel(
    const bf16* __restrict__ An, const bf16* __restrict__ Aa,
    const bf16* __restrict__ Bn, const bf16* __restrict__ Ba,
    const bf16* __restrict__ Bv,
    const float* __restrict__ bn, const float* __restrict__ ba,
    const float* __restrict__ bv,
    bf16* __restrict__ Kb, bf16* __restrict__ Qb, bf16* __restrict__ Vt) {
  const int t = threadIdx.x;
  const int lane = t & 63;
  const int w = t >> 6;
  const int l15 = lane & 15, g4 = lane >> 4;
  const int i0 = blockIdx.x * 64 + w * 16;
  const int y  = blockIdx.y;

  f32x4 acc[4];
#pragma unroll
  for (int s = 0; s < 4; ++s) acc[s] = (f32x4){0.f, 0.f, 0.f, 0.f};

  if (y < 8 || y >= 16) {  // KE = 128 paths
    const bf16* A = An;
    const bf16* B = (y < 8) ? Bn : Bv;
    const int o0 = (y < 8) ? y * 64 : (y - 16) * 64;
    const bf16* arow = A + (size_t)(i0 + l15) * 128 + g4 * 8;
    const bf16* brow = B + (size_t)(o0 + l15) * 128 + g4 * 8;
#pragma unroll
    for (int ks = 0; ks < 4; ++ks) {
      const short8 af = *reinterpret_cast<const short8*>(arow + ks * 32);
#pragma unroll
      for (int s = 0; s < 4; ++s) {
        const short8 bfr = *reinterpret_cast<const short8*>(
            brow + (size_t)s * 16 * 128 + ks * 32);
        acc[s] = __builtin_amdgcn_mfma_f32_16x16x32_bf16(af, bfr, acc[s], 0, 0, 0);
      }
    }
    if (y < 8) {  // nodes k/q epilogue
#pragma unroll
      for (int s = 0; s < 4; ++s) {
        const int o = o0 + s * 16 + l15;
        const float bb = bn[o];
        const int head = (o >> 6);
        const int half = (o >> 5) & 1;
        const int c = o & 31;
        bf16* dst = half ? Qb : Kb;
        const float sc = half ? 1.0f : KSC;
#pragma unroll
        for (int r = 0; r < 4; ++r)
          dst[(size_t)(i0 + g4 * 4 + r) * KQ_STRIDE + head * C + c] =
              __float2bfloat16((acc[s][r] + bb) * sc);
      }
    } else {  // val^T epilogue
#pragma unroll
      for (int s = 0; s < 4; ++s) {
        const int o = o0 + s * 16 + l15;
        const float bb = bv[o];
        s4v pk;
#pragma unroll
        for (int r = 0; r < 4; ++r) pk[r] = bf16_bits(acc[s][r] + bb);
        *reinterpret_cast<s4v*>(Vt + (size_t)o * S + i0 + g4 * 4) = pk;
      }
    }
  } else {  // aux path, KE = 32
    const int o0 = (y - 8) * 64;
    const bf16* arow = Aa + (size_t)(i0 + l15) * 32 + g4 * 8;
    const bf16* brow = Ba + (size_t)(o0 + l15) * 32 + g4 * 8;
    const short8 af = *reinterpret_cast<const short8*>(arow);
#pragma unroll
    for (int s = 0; s < 4; ++s) {
      const short8 bfr = *reinterpret_cast<const short8*>(
          brow + (size_t)s * 16 * 32);
      acc[s] = __builtin_amdgcn_mfma_f32_16x16x32_bf16(af, bfr, acc[s], 0, 0, 0);
    }
#pragma unroll
    for (int s = 0; s < 4; ++s) {
      const int o = o0 + s * 16 + l15;
      const float bb = ba[o];
      const int head = 8 + (o >> 6);
      const int half = (o >> 5) & 1;
      const int c = o & 31;
      bf16* dst = half ? Qb : Kb;
      const float sc = half ? 1.0f : KSC;
#pragma unroll
      for (int r = 0; r < 4; ++r)
        dst[(size_t)(i0 + g4 * 4 + r) * KQ_STRIDE + head * C + c] =
            __float2bfloat16((acc[s][r] + bb) * sc);
    }
  }
}

// ---------------------------------------------------------------------------
// Swapped-layout MFMA flash attention, XCD head-grouped, 128-j macro-tiles,
// LAZY softmax with hardware v_exp_f32 (exp2 domain). Defer-max, V via
// global_load_lds (pre-swizzled source), fp16 per-head partials.
// MODE 1: per-head fp16 O to Oph. MODE 2: atomicAdd float into out.
// ---------------------------------------------------------------------------
#define SF(q) sf[(q) >> 2][(q) & 3]
#define PSTR 76   // uint words per i-row

template <int MODE>
__global__ __launch_bounds__(256, 3) void attn_mfma_kernel(
    const bf16* __restrict__ Kb, const bf16* __restrict__ Qb,
    const bf16* __restrict__ Vt, const bf16* __restrict__ Ghat,
    const bf16* __restrict__ Rhat, __half* __restrict__ Oph,
    float* __restrict__ Opf) {
  // ---- XCD swizzle decode: id = within*8 + g; g -> heads [3g, 3g+3) ----
  const int id     = blockIdx.x;      // 0..767
  const int g      = id & 7;          // XCD under %8 round-robin
  const int within = id >> 3;         // 0..95
  const int h      = g * 3 + (within >> 5);
  const int i0     = (within & 31) * 64;

  const int t    = threadIdx.x;
  const int lane = t & 63;
  const int w    = t >> 6;
  const int l15  = lane & 15;
  const int g4   = lane >> 4;
  const bool isrot = (h >= 16);

  __shared__ __align__(16) bf16 Vs0[128 * 64];            // 16 KB each
  __shared__ __align__(16) bf16 Vs1[128 * 64];
  __shared__ __align__(16) unsigned int Ps[4][16][PSTR];  // 19 KB

  const bf16* kp; const bf16* qp; int qst;
  if (!isrot) {
    kp = Kb + h * C; qp = Qb + h * C; qst = KQ_STRIDE;
  } else {
    kp = Ghat + (size_t)(h - 16) * S * 32; qp = Rhat; qst = 32;
  }
  const int kst = isrot ? 32 : KQ_STRIDE;

  // B-frag: K row for this wave's i = i0 + w*16 + l15 (loop-invariant)
  const short8 kfrag = *reinterpret_cast<const short8*>(
      kp + (size_t)(i0 + w * 16 + l15) * kst + g4 * 8);

  float m = -1e30f, l = 0.0f;   // l is a PER-LANE partial (reduced at end)
  f32x4 oacc[8];
#pragma unroll
  for (int d = 0; d < 8; ++d) oacc[d] = (f32x4){0.f, 0.f, 0.f, 0.f};

  // ---- V staging source (pre-swizzled per-lane) ----
  const bf16* vglane = Vt + ((size_t)h * VD + w * 32 + (lane >> 3)) * S +
                       (((lane & 7) ^ ((lane >> 3) & 7)) << 3);
  const int vbase0 = l15 * 64 + (((g4 + 0) ^ (l15 & 7)) << 3);
  const int vbase1 = l15 * 64 + (((g4 + 4) ^ (l15 & 7)) << 3);

  const bf16* qlanebase = qp + (size_t)l15 * qst + g4 * 8;
  short8 qf[8];

  // ---- prologue: issue V gloads for macro 0 (both tiles); load Q macro 0 ----
  {
    bf16* d0 = Vs0 + (w << 11);
    bf16* d1 = Vs1 + (w << 11);
    gload_lds16(vglane,           d0);
    gload_lds16(vglane + 8 * S,   d0 + 512);
    gload_lds16(vglane + 16 * S,  d0 + 1024);
    gload_lds16(vglane + 24 * S,  d0 + 1536);
    gload_lds16(vglane + 64,          d1);
    gload_lds16(vglane + 64 + 8 * S,  d1 + 512);
    gload_lds16(vglane + 64 + 16 * S, d1 + 1024);
    gload_lds16(vglane + 64 + 24 * S, d1 + 1536);
  }
#pragma unroll
  for (int u = 0; u < 8; ++u)
    qf[u] = *reinterpret_cast<const short8*>(qlanebase + (size_t)(u * 16) * qst);

  for (int mt = 0; mt < S / 128; ++mt) {
    // ---- A: QK for both tiles (8 MFMA), scores S^T[j][i] ----
    f32x4 sf[8];
    {
      const f32x4 z = {0.f, 0.f, 0.f, 0.f};
      __builtin_amdgcn_s_setprio(1);
#pragma unroll
      for (int u = 0; u < 8; ++u)
        sf[u] = __builtin_amdgcn_mfma_f32_16x16x32_bf16(qf[u], kfrag, z, 0, 0, 0);
      __builtin_amdgcn_s_setprio(0);
    }
    // ---- B: reload Q for next macro ----
    if (mt + 1 < S / 128) {
      const bf16* qn = qlanebase + (size_t)((mt + 1) * 128) * qst;
#pragma unroll
      for (int u = 0; u < 8; ++u)
        qf[u] = *reinterpret_cast<const short8*>(qn + (size_t)(u * 16) * qst);
    }

    // ---- C: lazy softmax over 32 scores ----
    if (isrot) {
#pragma unroll
      for (int u = 0; u < 8; ++u)
#pragma unroll
        for (int r = 0; r < 4; ++r) sf[u][r] *= sf[u][r];
    }
    // lane-local max tree (depth 5)
    float tr[16];
#pragma unroll
    for (int q = 0; q < 16; ++q) tr[q] = fmaxf(SF(2 * q), SF(2 * q + 1));
#pragma unroll
    for (int st = 8; st >= 1; st >>= 1)
#pragma unroll
      for (int q = 0; q < 8; ++q)
        if (q < st) tr[q] = fmaxf(tr[q], tr[q + st]);
    const float tm = tr[0];
    // rescale check WITHOUT cross-lane reduce; row-max shfls only if firing
    if (__any(tm > m + 8.0f)) {
      float tmr = tm;
      tmr = fmaxf(tmr, __shfl_xor(tmr, 16));
      tmr = fmaxf(tmr, __shfl_xor(tmr, 32));
      const float mnew = fmaxf(m, tmr);
      const float corr = fexp2(m - mnew);
      m = mnew;
      l *= corr;
#pragma unroll
      for (int d = 0; d < 8; ++d)
#pragma unroll
        for (int r = 0; r < 4; ++r) oacc[d][r] *= corr;
    }
    // exp (independent) + lane-local sum tree into l partial
#pragma unroll
    for (int u = 0; u < 8; ++u)
#pragma unroll
      for (int r = 0; r < 4; ++r) sf[u][r] = fexp2(sf[u][r] - m);
    float sr[16];
#pragma unroll
    for (int q = 0; q < 16; ++q) sr[q] = SF(2 * q) + SF(2 * q + 1);
#pragma unroll
    for (int st = 8; st >= 1; st >>= 1)
#pragma unroll
      for (int q = 0; q < 8; ++q)
        if (q < st) sr[q] = sr[q] + sr[q + st];
    l += sr[0];

    // ---- pack P (both tiles) into Ps; per-wave region ----
#pragma unroll
    for (int sub = 0; sub < 8; ++sub) {
      unsigned int u0, u1;
      asm volatile("v_cvt_pk_bf16_f32 %0, %1, %2"
                   : "=v"(u0) : "v"(SF(4 * sub)), "v"(SF(4 * sub + 1)));
      asm volatile("v_cvt_pk_bf16_f32 %0, %1, %2"
                   : "=v"(u1) : "v"(SF(4 * sub + 2)), "v"(SF(4 * sub + 3)));
      uint2 pk; pk.x = u0; pk.y = u1;
      const int col = (sub < 4 ? sub * 8 : 40 + (sub - 4) * 8) + g4 * 2;
      *reinterpret_cast<uint2*>(&Ps[w][l15][col]) = pk;
    }

    // ---- D: barrier (drains V gloads; P visible) ----
    __syncthreads();

    // ---- E: PV both tiles (32 MFMA) ----
    {
      union { uint4 u; short8 s; } pb0, pb1, pb2, pb3;
      pb0.u = *reinterpret_cast<const uint4*>(&Ps[w][l15][g4 * 4]);
      pb1.u = *reinterpret_cast<const uint4*>(&Ps[w][l15][16 + g4 * 4]);
      pb2.u = *reinterpret_cast<const uint4*>(&Ps[w][l15][40 + g4 * 4]);
      pb3.u = *reinterpret_cast<const uint4*>(&Ps[w][l15][56 + g4 * 4]);
      __builtin_amdgcn_s_setprio(1);
#pragma unroll
      for (int dsub = 0; dsub < 8; ++dsub) {
        const short8 va = *reinterpret_cast<const short8*>(
            &Vs0[vbase0 + dsub * 1024]);
        oacc[dsub] =
            __builtin_amdgcn_mfma_f32_16x16x32_bf16(va, pb0.s, oacc[dsub], 0, 0, 0);
      }
#pragma unroll
      for (int dsub = 0; dsub < 8; ++dsub) {
        const short8 va = *reinterpret_cast<const short8*>(
            &Vs0[vbase1 + dsub * 1024]);
        oacc[dsub] =
            __builtin_amdgcn_mfma_f32_16x16x32_bf16(va, pb1.s, oacc[dsub], 0, 0, 0);
      }
#pragma unroll
      for (int dsub = 0; dsub < 8; ++dsub) {
        const short8 va = *reinterpret_cast<const short8*>(
            &Vs1[vbase0 + dsub * 1024]);
        oacc[dsub] =
            __builtin_amdgcn_mfma_f32_16x16x32_bf16(va, pb2.s, oacc[dsub], 0, 0, 0);
      }
#pragma unroll
      for (int dsub = 0; dsub < 8; ++dsub) {
        const short8 va = *reinterpret_cast<const short8*>(
            &Vs1[vbase1 + dsub * 1024]);
        oacc[dsub] =
            __builtin_amdgcn_mfma_f32_16x16x32_bf16(va, pb3.s, oacc[dsub], 0, 0, 0);
      }
      __builtin_amdgcn_s_setprio(0);
    }

    // ---- F: barrier (all waves' PV reads done) ----
    __syncthreads();

    // ---- G: issue async V gloads for next macro ----
    if (mt + 1 < S / 128) {
      const bf16* gsrc = vglane + (size_t)(mt + 1) * 128;
      bf16* d0 = Vs0 + (w << 11);
      bf16* d1 = Vs1 + (w << 11);
      gload_lds16(gsrc,           d0);
      gload_lds16(gsrc + 8 * S,   d0 + 512);
      gload_lds16(gsrc + 16 * S,  d0 + 1024);
      gload_lds16(gsrc + 24 * S,  d0 + 1536);
      gload_lds16(gsrc + 64,          d1);
      gload_lds16(gsrc + 64 + 8 * S,  d1 + 512);
      gload_lds16(gsrc + 64 + 16 * S, d1 + 1024);
      gload_lds16(gsrc + 64 + 24 * S, d1 + 1536);
    }
  }

  // ---- epilogue: reduce per-lane l partials across the row's 4 lanes ----
  l += __shfl_xor(l, 16);
  l += __shfl_xor(l, 32);
  const float inv = 1.0f / l;
  const int irow = i0 + w * 16 + l15;
  if (MODE == 2) {
#pragma unroll
    for (int dsub = 0; dsub < 8; ++dsub)
#pragma unroll
      for (int r = 0; r < 4; ++r)
        atomicAdd(Opf + (size_t)irow * VD + dsub * 16 + g4 * 4 + r,
                  oacc[dsub][r] * inv);
  } else {
    __half* op = Oph + (size_t)h * (S * VD) + (size_t)irow * VD;
#pragma unroll
    for (int dsub = 0; dsub < 8; ++dsub) {
      __half h0 = __float2half(oacc[dsub][0] * inv);
      __half h1 = __float2half(oacc[dsub][1] * inv);
      __half h2 = __float2half(oacc[dsub][2] * inv);
      __half h3 = __float2half(oacc[dsub][3] * inv);
      __half2 p0 = __halves2half2(h0, h1);
      __half2 p1 = __halves2half2(h2, h3);
      uint2 u;
      u.x = *reinterpret_cast<unsigned int*>(&p0);
      u.y = *reinterpret_cast<unsigned int*>(&p1);
      *reinterpret_cast<uint2*>(op + dsub * 16 + g4 * 4) = u;
    }
  }
}

// Sum the 24 per-head fp16 partials into the final (S, 128) fp32 output.
__global__ __launch_bounds__(256) void reduce_out_kernel(
    const __half* __restrict__ Op, float* __restrict__ out) {
  const int idx2 = (blockIdx.x * 256 + threadIdx.x) * 2;
  float s0 = 0.0f, s1 = 0.0f;
#pragma unroll
  for (int hh = 0; hh < NH; ++hh) {
    const __half2 hv = *reinterpret_cast<const __half2*>(
        Op + (size_t)hh * (S * VD) + idx2);
    const float2 f = __half22float2(hv);
    s0 += f.x;
    s1 += f.y;
  }
  float2 o; o.x = s0; o.y = s1;
  *reinterpret_cast<float2*>(out + idx2) = o;
}

extern "C" void kernel_launch(void* const* d_in, const int* in_sizes, int n_in,
                              void* d_out, int out_size, void* d_ws, size_t ws_size,
                              hipStream_t stream) {
  const float* nodes = (const float*)d_in[0];
  const float* aux   = (const float*)d_in[1];
  const float* rot   = (const float*)d_in[2];
  const float* Wn    = (const float*)d_in[3];
  const float* bn    = (const float*)d_in[4];
  const float* Wa    = (const float*)d_in[5];
  const float* ba    = (const float*)d_in[6];
  const float* Wr    = (const float*)d_in[7];
  const float* Wv    = (const float*)d_in[8];
  const float* bv    = (const float*)d_in[9];
  float* out = (float*)d_out;

  char* ws = (char*)d_ws;
  const size_t off_conv = 0;
  const size_t off_Kb   = off_conv + (size_t)CONV_TOTAL * 2;
  const size_t off_Qb   = off_Kb + (size_t)S * KQ_STRIDE * 2;
  const size_t off_Vt   = off_Qb + (size_t)S * KQ_STRIDE * 2;
  const size_t off_Gh   = off_Vt + (size_t)NH * VD * S * 2;
  const size_t off_Rh   = off_Gh + (size_t)8 * S * 32 * 2;
  const size_t off_Op   = off_Rh + (size_t)S * 32 * 2;
  const size_t need1    = off_Op + (size_t)NH * S * VD * 2;   // fp16 partials

  bf16* convb = (bf16*)(ws + off_conv);
  bf16* An = convb;
  bf16* Aa = convb + AN_SZ;
  bf16* Bn = convb + AN_SZ + AA_SZ;
  bf16* Ba = convb + AN_SZ + AA_SZ + BN_SZ;
  bf16* Bv = convb + AN_SZ + AA_SZ + BN_SZ + BA_SZ;
  bf16*  Kb = (bf16*)(ws + off_Kb);
  bf16*  Qb = (bf16*)(ws + off_Qb);
  bf16*  Vt = (bf16*)(ws + off_Vt);
  bf16*  Gh = (bf16*)(ws + off_Gh);
  bf16*  Rh = (bf16*)(ws + off_Rh);
  __half* Oph = (__half*)(ws + off_Op);

  prep_kernel<<<CONV_BLOCKS + S / 32, 256, 0, stream>>>(
      nodes, aux, Wn, Wa, Wv, rot, Wr, convb, Gh, Rh);

  proj_all_kernel<<<dim3(S / 64, 64), 256, 0, stream>>>(
      An, Aa, Bn, Ba, Bv, bn, ba, bv, Kb, Qb, Vt);

  if (ws_size >= need1) {
    attn_mfma_kernel<1><<<dim3(768), 256, 0, stream>>>(
        Kb, Qb, Vt, Gh, Rh, Oph, nullptr);
    reduce_out_kernel<<<(S * VD) / 512, 256, 0, stream>>>(Oph, out);
  } else {
    hipMemsetAsync(d_out, 0, (size_t)out_size * sizeof(float), stream);
    attn_mfma_kernel<2><<<dim3(768), 256, 0, stream>>>(
        Kb, Qb, Vt, Gh, Rh, nullptr, out);
  }
}